// Round 1
// baseline (441.961 us; speedup 1.0000x reference)
//
#include <hip/hip_runtime.h>
#include <hip/hip_bf16.h>

#define NN      50000
#define INDIM   512
#define HIDDEN  256
#define NE      800000
#define BIASF   0.0001f

typedef __attribute__((ext_vector_type(4))) float  f32x4;
typedef __attribute__((ext_vector_type(4))) __bf16 bf16x4;
typedef __attribute__((ext_vector_type(8))) __bf16 bf16x8;

// ---------------------------------------------------------------------------
// prep: Wt[n][k] = W_emb[k][n] (fp32, 256x512) ; w_sym[j] = 0.5*(We[j]+We[j+256])
// ---------------------------------------------------------------------------
__global__ __launch_bounds__(256) void prep_kernel(const float* __restrict__ W_emb,
                                                   const float* __restrict__ W_edge,
                                                   float* __restrict__ Wt,
                                                   float* __restrict__ w_sym) {
    int idx = blockIdx.x * 256 + threadIdx.x;      // 512 blocks -> 131072 threads
    if (idx < HIDDEN * INDIM) {
        int n = idx >> 9;                           // / 512
        int k = idx & 511;
        Wt[idx] = W_emb[k * HIDDEN + n];
    }
    if (idx < HIDDEN) {
        w_sym[idx] = 0.5f * (W_edge[idx] + W_edge[idx + HIDDEN]);
    }
}

// ---------------------------------------------------------------------------
// GEMM: h[m][n] = relu(emb[m][:] @ W[:][n] + b[n]), bf16 MFMA 16x16x32.
// BM=BN=128, BK=32. 4 waves, each computes a 64x64 quadrant as 4x4 MFMA tiles.
// fp32 loaded from global, converted to bf16 while staging into LDS.
// LDS row stride 40 elems (80 B) keeps 16B alignment and breaks pow2 banks.
// ---------------------------------------------------------------------------
__global__ __launch_bounds__(256) void gemm_h_kernel(const float* __restrict__ A,
                                                     const float* __restrict__ Wt,
                                                     const float* __restrict__ bias,
                                                     __bf16* __restrict__ h) {
    constexpr int BM = 128, BK = 32, LDT = 40;
    __shared__ __align__(16) __bf16 As[BM * LDT];
    __shared__ __align__(16) __bf16 Bs[BM * LDT];

    const int tid  = threadIdx.x;
    const int lane = tid & 63;
    const int w    = tid >> 6;
    const int wm   = w >> 1, wn = w & 1;
    const int m0   = blockIdx.y * BM;
    const int n0   = blockIdx.x * BM;
    const int ml   = lane & 15, kq = lane >> 4;

    f32x4 acc[4][4];
#pragma unroll
    for (int i = 0; i < 4; ++i)
#pragma unroll
        for (int j = 0; j < 4; ++j) acc[i][j] = (f32x4)0.0f;

    for (int kt = 0; kt < INDIM; kt += BK) {
        // ---- stage A and B tiles (1024 float4 each, 4 per thread) ----
#pragma unroll
        for (int it = 0; it < 4; ++it) {
            int i  = it * 256 + tid;
            int r  = i >> 3;
            int c4 = (i & 7) << 2;
            int gr = m0 + r; if (gr > NN - 1) gr = NN - 1;   // clamp M tail
            f32x4 va = *(const f32x4*)(A + (size_t)gr * INDIM + kt + c4);
            bf16x4 ba;
            ba[0] = (__bf16)va[0]; ba[1] = (__bf16)va[1];
            ba[2] = (__bf16)va[2]; ba[3] = (__bf16)va[3];
            *(bf16x4*)&As[r * LDT + c4] = ba;

            f32x4 vb = *(const f32x4*)(Wt + (size_t)(n0 + r) * INDIM + kt + c4);
            bf16x4 bb;
            bb[0] = (__bf16)vb[0]; bb[1] = (__bf16)vb[1];
            bb[2] = (__bf16)vb[2]; bb[3] = (__bf16)vb[3];
            *(bf16x4*)&Bs[r * LDT + c4] = bb;
        }
        __syncthreads();

        // ---- fragments + 16 MFMAs ----
        bf16x8 af[4], bfr[4];
#pragma unroll
        for (int mt = 0; mt < 4; ++mt)
            af[mt] = *(const bf16x8*)&As[(wm * 64 + mt * 16 + ml) * LDT + kq * 8];
#pragma unroll
        for (int nt = 0; nt < 4; ++nt)
            bfr[nt] = *(const bf16x8*)&Bs[(wn * 64 + nt * 16 + ml) * LDT + kq * 8];
#pragma unroll
        for (int mt = 0; mt < 4; ++mt)
#pragma unroll
            for (int nt = 0; nt < 4; ++nt)
                acc[mt][nt] = __builtin_amdgcn_mfma_f32_16x16x32_bf16(
                    af[mt], bfr[nt], acc[mt][nt], 0, 0, 0);
        __syncthreads();
    }

    // ---- epilogue: +bias, relu, bf16 store. C/D: col=lane&15, row=kq*4+reg ----
#pragma unroll
    for (int mt = 0; mt < 4; ++mt) {
        int rbase = m0 + wm * 64 + mt * 16 + kq * 4;
#pragma unroll
        for (int nt = 0; nt < 4; ++nt) {
            int col = n0 + wn * 64 + nt * 16 + ml;
            float bc = bias[col];
#pragma unroll
            for (int r = 0; r < 4; ++r) {
                int row = rbase + r;
                if (row < NN) {
                    float x = acc[mt][nt][r] + bc;
                    h[(size_t)row * HIDDEN + col] = (__bf16)fmaxf(x, 0.0f);
                }
            }
        }
    }
}

// ---------------------------------------------------------------------------
// edge kernel: one wave per edge. lane i holds 4 bf16 of each gathered row.
// raw = (h0+h1)�w_sym + b ; gate = log(eps)-log1p(-eps)+raw ; out = sigmoid
// ---------------------------------------------------------------------------
__global__ __launch_bounds__(256) void edge_kernel(const __bf16* __restrict__ h,
                                                   const int* __restrict__ edges,
                                                   const float* __restrict__ u,
                                                   const float* __restrict__ w_sym,
                                                   const float* __restrict__ b_edge,
                                                   float* __restrict__ out) {
    const int lane = threadIdx.x & 63;
    const int wv   = threadIdx.x >> 6;
    const int e    = blockIdx.x * 4 + wv;           // NE divisible by 4

    const int i0 = edges[e];
    const int i1 = edges[NE + e];

    bf16x4 a = *(const bf16x4*)(h + (size_t)i0 * HIDDEN + lane * 4);
    bf16x4 b = *(const bf16x4*)(h + (size_t)i1 * HIDDEN + lane * 4);
    f32x4  w = *(const f32x4*)(w_sym + lane * 4);

    float s = ((float)a[0] + (float)b[0]) * w[0]
            + ((float)a[1] + (float)b[1]) * w[1]
            + ((float)a[2] + (float)b[2]) * w[2]
            + ((float)a[3] + (float)b[3]) * w[3];

#pragma unroll
    for (int off = 32; off > 0; off >>= 1) s += __shfl_down(s, off);

    if (lane == 0) {
        float raw = s + b_edge[0];
        float uu  = u[e];
        float eps = fmaf(uu, BIASF - (1.0f - BIASF), 1.0f - BIASF); // -0.9998u+0.9999
        float g   = logf(eps) - log1pf(-eps) + raw;                 // TEMPERATURE=1
        out[e] = 1.0f / (1.0f + expf(-g));
    }
}

// ---------------------------------------------------------------------------
extern "C" void kernel_launch(void* const* d_in, const int* in_sizes, int n_in,
                              void* d_out, int out_size, void* d_ws, size_t ws_size,
                              hipStream_t stream) {
    const float* embedding = (const float*)d_in[0];
    const int*   edges     = (const int*)d_in[1];
    const float* u         = (const float*)d_in[2];
    const float* W_emb     = (const float*)d_in[3];
    const float* b_emb     = (const float*)d_in[4];
    const float* W_edge    = (const float*)d_in[5];
    const float* b_edge    = (const float*)d_in[6];
    float*       out       = (float*)d_out;

    // workspace layout
    char*   ws    = (char*)d_ws;
    __bf16* h     = (__bf16*)ws;                                 // 25,600,000 B
    float*  Wt    = (float*)(ws + 25600000);                     //    524,288 B
    float*  w_sym = (float*)(ws + 25600000 + 524288);            //      1,024 B

    prep_kernel<<<512, 256, 0, stream>>>(W_emb, W_edge, Wt, w_sym);

    dim3 ggrid(2, 391);   // x = N-block (2), y = M-block (391) -> N blocks adjacent for L2 reuse of A
    gemm_h_kernel<<<ggrid, 256, 0, stream>>>(embedding, Wt, b_emb, h);

    edge_kernel<<<NE / 4, 256, 0, stream>>>(h, edges, u, w_sym, b_edge, out);
}

// Round 2
// 204.332 us; speedup vs baseline: 2.1630x; 2.1630x over previous
//
#include <hip/hip_runtime.h>
#include <hip/hip_bf16.h>

#define NN      50000
#define INDIM   512
#define HIDDEN  256
#define NE      800000
#define BIASF   0.0001f

typedef __attribute__((ext_vector_type(4))) float  f32x4;
typedef __attribute__((ext_vector_type(4))) __bf16 bf16x4;
typedef __attribute__((ext_vector_type(8))) __bf16 bf16x8;

// ---------------------------------------------------------------------------
// prep: Wt[n][k] = W_emb[k][n] (fp32, 256x512) ; w_sym[j] = 0.5*(We[j]+We[j+256])
//       and zero g[NN] (ws is re-poisoned to 0xAA before every call)
// ---------------------------------------------------------------------------
__global__ __launch_bounds__(256) void prep_kernel(const float* __restrict__ W_emb,
                                                   const float* __restrict__ W_edge,
                                                   float* __restrict__ Wt,
                                                   float* __restrict__ w_sym,
                                                   float* __restrict__ g) {
    int idx = blockIdx.x * 256 + threadIdx.x;      // 512 blocks -> 131072 threads
    if (idx < HIDDEN * INDIM) {
        int n = idx >> 9;                           // / 512
        int k = idx & 511;
        Wt[idx] = W_emb[k * HIDDEN + n];
    }
    if (idx < HIDDEN) {
        w_sym[idx] = 0.5f * (W_edge[idx] + W_edge[idx + HIDDEN]);
    }
    if (idx < NN) {
        g[idx] = 0.0f;
    }
}

// ---------------------------------------------------------------------------
// GEMM + fused node-dot: g[m] += sum_n relu(emb[m]@W[:,n] + b[n]) * w_sym[n]
// bf16 MFMA 16x16x32, BM=BN=128, BK=32, 4 waves each owning a 64x64 quadrant.
// h is NEVER materialized. Two blocks (grid.x=2) contribute per row -> atomicAdd.
// ---------------------------------------------------------------------------
__global__ __launch_bounds__(256) void gemm_g_kernel(const float* __restrict__ A,
                                                     const float* __restrict__ Wt,
                                                     const float* __restrict__ bias,
                                                     const float* __restrict__ w_sym,
                                                     float* __restrict__ g) {
    constexpr int BM = 128, BK = 32, LDT = 40;
    __shared__ __align__(16) __bf16 As[BM * LDT];
    __shared__ __align__(16) __bf16 Bs[BM * LDT];

    const int tid  = threadIdx.x;
    const int lane = tid & 63;
    const int w    = tid >> 6;
    const int wm   = w >> 1, wn = w & 1;
    const int m0   = blockIdx.y * BM;
    const int n0   = blockIdx.x * BM;
    const int ml   = lane & 15, kq = lane >> 4;

    f32x4 acc[4][4];
#pragma unroll
    for (int i = 0; i < 4; ++i)
#pragma unroll
        for (int j = 0; j < 4; ++j) acc[i][j] = (f32x4)0.0f;

    for (int kt = 0; kt < INDIM; kt += BK) {
        // ---- stage A and B tiles (1024 float4 each, 4 per thread) ----
#pragma unroll
        for (int it = 0; it < 4; ++it) {
            int i  = it * 256 + tid;
            int r  = i >> 3;
            int c4 = (i & 7) << 2;
            int gr = m0 + r; if (gr > NN - 1) gr = NN - 1;   // clamp M tail
            f32x4 va = *(const f32x4*)(A + (size_t)gr * INDIM + kt + c4);
            bf16x4 ba;
            ba[0] = (__bf16)va[0]; ba[1] = (__bf16)va[1];
            ba[2] = (__bf16)va[2]; ba[3] = (__bf16)va[3];
            *(bf16x4*)&As[r * LDT + c4] = ba;

            f32x4 vb = *(const f32x4*)(Wt + (size_t)(n0 + r) * INDIM + kt + c4);
            bf16x4 bb;
            bb[0] = (__bf16)vb[0]; bb[1] = (__bf16)vb[1];
            bb[2] = (__bf16)vb[2]; bb[3] = (__bf16)vb[3];
            *(bf16x4*)&Bs[r * LDT + c4] = bb;
        }
        __syncthreads();

        // ---- fragments + 16 MFMAs ----
        bf16x8 af[4], bfr[4];
#pragma unroll
        for (int mt = 0; mt < 4; ++mt)
            af[mt] = *(const bf16x8*)&As[(wm * 64 + mt * 16 + ml) * LDT + kq * 8];
#pragma unroll
        for (int nt = 0; nt < 4; ++nt)
            bfr[nt] = *(const bf16x8*)&Bs[(wn * 64 + nt * 16 + ml) * LDT + kq * 8];
#pragma unroll
        for (int mt = 0; mt < 4; ++mt)
#pragma unroll
            for (int nt = 0; nt < 4; ++nt)
                acc[mt][nt] = __builtin_amdgcn_mfma_f32_16x16x32_bf16(
                    af[mt], bfr[nt], acc[mt][nt], 0, 0, 0);
        __syncthreads();
    }

    // ---- epilogue: per-row partial dot with w_sym, xor-shuffle reduce over
    //      the 16 lanes (ml) that share a row, atomicAdd into g.
    //      C/D layout: col = lane&15 (ml), row = kq*4 + reg  [verified m89/m91]
    float wsv[4], bcv[4];
#pragma unroll
    for (int nt = 0; nt < 4; ++nt) {
        int col = n0 + wn * 64 + nt * 16 + ml;
        wsv[nt] = w_sym[col];
        bcv[nt] = bias[col];
    }
#pragma unroll
    for (int mt = 0; mt < 4; ++mt) {
#pragma unroll
        for (int r = 0; r < 4; ++r) {
            float s = 0.0f;
#pragma unroll
            for (int nt = 0; nt < 4; ++nt) {
                float x = acc[mt][nt][r] + bcv[nt];
                s = fmaf(fmaxf(x, 0.0f), wsv[nt], s);
            }
            s += __shfl_xor(s, 1);
            s += __shfl_xor(s, 2);
            s += __shfl_xor(s, 4);
            s += __shfl_xor(s, 8);
            int row = m0 + wm * 64 + mt * 16 + kq * 4 + r;
            if (ml == 0 && row < NN) atomicAdd(&g[row], s);
        }
    }
}

// ---------------------------------------------------------------------------
// edge kernel: one THREAD per edge. g gathers are 4B from a 200 KB array ->
// L2-resident on every XCD. Streaming: edges 6.4MB + u 3.2MB + out 3.2MB.
// ---------------------------------------------------------------------------
__global__ __launch_bounds__(256) void edge_kernel(const float* __restrict__ g,
                                                   const int* __restrict__ edges,
                                                   const float* __restrict__ u,
                                                   const float* __restrict__ b_edge,
                                                   float* __restrict__ out) {
    const int e = blockIdx.x * 256 + threadIdx.x;   // NE = 3125*256 exactly
    const int i0 = edges[e];
    const int i1 = edges[NE + e];
    float raw = g[i0] + g[i1] + b_edge[0];
    float uu  = u[e];
    float eps = fmaf(uu, BIASF - (1.0f - BIASF), 1.0f - BIASF); // -0.9998u+0.9999
    float gt  = logf(eps) - log1pf(-eps) + raw;                 // TEMPERATURE=1
    out[e] = 1.0f / (1.0f + expf(-gt));
}

// ---------------------------------------------------------------------------
extern "C" void kernel_launch(void* const* d_in, const int* in_sizes, int n_in,
                              void* d_out, int out_size, void* d_ws, size_t ws_size,
                              hipStream_t stream) {
    const float* embedding = (const float*)d_in[0];
    const int*   edges     = (const int*)d_in[1];
    const float* u         = (const float*)d_in[2];
    const float* W_emb     = (const float*)d_in[3];
    const float* b_emb     = (const float*)d_in[4];
    const float* W_edge    = (const float*)d_in[5];
    const float* b_edge    = (const float*)d_in[6];
    float*       out       = (float*)d_out;

    // workspace layout (well under the ~26 MB proven available in round 1)
    char*  ws    = (char*)d_ws;
    float* Wt    = (float*)ws;                       // 524,288 B
    float* w_sym = (float*)(ws + 524288);            //   1,024 B
    float* g     = (float*)(ws + 524288 + 1024);     // 200,000 B

    prep_kernel<<<512, 256, 0, stream>>>(W_emb, W_edge, Wt, w_sym, g);

    dim3 ggrid(2, 391);   // x = N-block, y = M-block
    gemm_g_kernel<<<ggrid, 256, 0, stream>>>(embedding, Wt, b_emb, w_sym, g);

    edge_kernel<<<NE / 256, 256, 0, stream>>>(g, edges, u, b_edge, out);
}